// Round 5
// baseline (117766.028 us; speedup 1.0000x reference)
//
#include <hip/hip_runtime.h>
#include <cstdint>
#include <cstddef>

#define SEQ       32768
#define NT        512
#define START_TAG 510
#define END_TAG   511
#define NEGF      -10000.0f
#define KCH       64
#define NCH       (SEQ / KCH)   /* 512 chunks */
#define NWG       128           /* forward waves (1 wave per WG) */
#define RPW       4             /* rows per wave */

/* workspace layout
   bp : 32 MiB  backpointers (u16)
   M  : 512 KiB chunk-composed maps
   bd : 2 KiB   chunk boundary tags
   Ag : 8 KiB   tagged alpha ping-pong: u64 = (tag << 32) | f32bits          */
#define BP_BYTES  ((size_t)SEQ * NT * sizeof(unsigned short))
#define M_OFF     (BP_BYTES)
#define M_BYTES   ((size_t)NCH * NT * sizeof(unsigned short))
#define BD_OFF    (M_OFF + M_BYTES)
#define BD_BYTES  ((size_t)NCH * sizeof(int))
#define AG_OFF    ((BD_OFF + BD_BYTES + 63) & ~(size_t)63)

/* ---------- kernel 0: init tagged alpha_0 ---------- */
__global__ __launch_bounds__(NT) void init_k(unsigned long long* Ag) {
    const int j = threadIdx.x;
    const float a0 = (j == START_TAG) ? 0.0f : NEGF;
    Ag[j]      = (1ull << 32) | (unsigned long long)__float_as_uint(a0); /* tag 1 */
    Ag[NT + j] = 0ull;                                                  /* invalid */
}

/* ---------- kernel 1: self-timed dataflow Viterbi forward ----------
   128 single-wave WGs; WG b owns output rows [4b, 4b+4). No barriers, no
   flags: alpha elements carry their step tag in the same 8-byte atom.
   Lane polls exactly the 8 alpha elements it consumes (i = lane + 64k).
   Two buffers are safe: advancing past step t requires observing all tags
   t+1, which implies every wave finished its step-t reads (data dep).     */
__global__ __launch_bounds__(64) void viterbi_fwd(const float* __restrict__ u,
                                                  const float* __restrict__ tr,
                                                  unsigned short* __restrict__ bp,
                                                  unsigned long long* Ag) {
    const int lane = threadIdx.x;
    const int r0   = (int)blockIdx.x * RPW;

    /* preload this wave's 4 transition rows into registers (8 KB -> 32 VGPR) */
    float trr[RPW][8];
    #pragma unroll
    for (int r = 0; r < RPW; ++r)
        #pragma unroll
        for (int k = 0; k < 8; ++k)
            trr[r][k] = tr[(size_t)(r0 + r) * NT + lane + (k << 6)];

    float uc = (lane < RPW) ? u[r0 + lane] : 0.0f;   /* u[0, own row] */

    for (int t = 0; t < SEQ; ++t) {
        /* prefetch next step's unary (overlaps the poll) */
        float un = 0.0f;
        if (lane < RPW && (t + 1) < SEQ) un = u[(size_t)(t + 1) * NT + r0 + lane];

        /* poll own 8 alpha elements of step t (tag t+1), single buffer read */
        const unsigned long long want = (unsigned long long)(t + 1);
        const unsigned long long* Ab = Ag + ((t & 1) ? NT : 0);
        unsigned long long av[8];
        for (;;) {
            bool ok = true;
            #pragma unroll
            for (int k = 0; k < 8; ++k) {
                av[k] = __hip_atomic_load(&Ab[lane + (k << 6)],
                                          __ATOMIC_RELAXED, __HIP_MEMORY_SCOPE_AGENT);
                ok &= ((av[k] >> 32) == want);
            }
            if (__all(ok)) break;
        }
        float al[8];
        #pragma unroll
        for (int k = 0; k < 8; ++k) al[k] = __uint_as_float((unsigned)av[k]);

        /* 4 rows: per-lane ascending-k scan (ascending i within lane, strict '>'
           keeps lowest i), then cross-lane butterfly with (val desc, idx asc). */
        float res[RPW]; int resi[RPW];
        #pragma unroll
        for (int r = 0; r < RPW; ++r) {
            float bv = al[0] + trr[r][0]; int bi = lane;
            #pragma unroll
            for (int k = 1; k < 8; ++k) {
                const float s = al[k] + trr[r][k];
                if (s > bv) { bv = s; bi = lane + (k << 6); }
            }
            #pragma unroll
            for (int off = 1; off < 64; off <<= 1) {
                const float ov = __shfl_xor(bv, off);
                const int   oi = __shfl_xor(bi, off);
                if (ov > bv || (ov == bv && oi < bi)) { bv = ov; bi = oi; }
            }
            res[r] = bv; resi[r] = bi;
        }

        /* backpointers: 4 contiguous u16 -> one 8B store by lane 0 */
        if (lane == 0) {
            const unsigned long long pk =
                (unsigned long long)(unsigned short)resi[0]
              | ((unsigned long long)(unsigned short)resi[1] << 16)
              | ((unsigned long long)(unsigned short)resi[2] << 32)
              | ((unsigned long long)(unsigned short)resi[3] << 48);
            *reinterpret_cast<unsigned long long*>(bp + (size_t)t * NT + r0) = pk;
        }

        /* publish alpha_{t+1}[own rows] tagged t+2 (data+tag in one atom) */
        if (lane < RPW) {
            const float na = res[lane] + uc;          /* fl(vit + u_t[j]) */
            const unsigned long long pv =
                ((unsigned long long)(t + 2) << 32)
              | (unsigned long long)__float_as_uint(na);
            __hip_atomic_store(&Ag[(size_t)((t + 1) & 1) * NT + r0 + lane], pv,
                               __ATOMIC_RELAXED, __HIP_MEMORY_SCOPE_AGENT);
        }
        uc = un;
    }
}

/* ---------- kernel 2: parallel chunk-map composition from bp ---------- */
__global__ __launch_bounds__(NT) void mbuild_k(const unsigned short* __restrict__ bp,
                                               unsigned short* __restrict__ M) {
    __shared__ unsigned short R[2][NT];
    const int c = (int)blockIdx.x, j = threadIdx.x;
    const size_t base = (size_t)c * KCH * NT;
    R[0][j] = bp[base + j];
    int cb = 0;
    for (int t = 1; t < KCH; ++t) {
        const unsigned short r = bp[base + (size_t)t * NT + j];
        __syncthreads();
        R[cb ^ 1][j] = R[cb][r];
        cb ^= 1;
    }
    __syncthreads();
    M[(size_t)c * NT + j] = R[cb][j];
}

/* ---------- kernel 3: terminal argmax + chunk-boundary chase ---------- */
__global__ __launch_bounds__(NT) void chase_k(const unsigned long long* __restrict__ Ag,
                                              const float* __restrict__ tr,
                                              const unsigned short* __restrict__ M,
                                              int* __restrict__ boundary,
                                              float* __restrict__ out) {
    __shared__ float sv[NT];
    __shared__ int   si[NT];
    const int j = threadIdx.x;
    /* alpha_SEQ sits in buffer SEQ&1 == 0, tagged SEQ+1; strip the tag */
    const float aj = __uint_as_float((unsigned)Ag[j]);
    sv[j] = aj + tr[(size_t)END_TAG * NT + j];
    si[j] = j;
    __syncthreads();
    for (int off = NT / 2; off > 0; off >>= 1) {
        if (j < off) {
            const float a = sv[j], b = sv[j + off];
            if (b > a || (b == a && si[j + off] < si[j])) { sv[j] = b; si[j] = si[j + off]; }
        }
        __syncthreads();
    }
    if (j == 0) {
        out[SEQ] = sv[0];                 /* path_score */
        int tag = si[0];                  /* path[32767] */
        boundary[NCH - 1] = tag;
        for (int c = NCH - 1; c >= 1; --c) {
            tag = (int)M[(size_t)c * NT + tag];
            boundary[c - 1] = tag;
        }
    }
}

/* ---------- kernel 4: 512 independent per-chunk local tracebacks ---------- */
__global__ __launch_bounds__(64) void traceback_k(const unsigned short* __restrict__ bp,
                                                  const int* __restrict__ boundary,
                                                  float* __restrict__ out) {
    if (threadIdx.x != 0) return;
    const int c    = (int)blockIdx.x;
    int       tag  = boundary[c];            /* = path[(c+1)K - 1] */
    const int tend = (c + 1) * KCH - 1;
    out[tend] = (float)tag;
    for (int t = tend - 1; t >= c * KCH; --t) {
        tag = (int)bp[(size_t)(t + 1) * NT + tag];
        out[t] = (float)tag;
    }
}

extern "C" void kernel_launch(void* const* d_in, const int* in_sizes, int n_in,
                              void* d_out, int out_size, void* d_ws, size_t ws_size,
                              hipStream_t stream) {
    const float* unary = (const float*)d_in[0];   /* (32768,1,512) f32 */
    const float* trans = (const float*)d_in[1];   /* (1,512,512)   f32 */
    float* out = (float*)d_out;                   /* [0..32767]=path, [32768]=score */
    char*  ws  = (char*)d_ws;

    unsigned short*     bp       = (unsigned short*)ws;
    unsigned short*     M        = (unsigned short*)(ws + M_OFF);
    int*                boundary = (int*)(ws + BD_OFF);
    unsigned long long* Ag       = (unsigned long long*)(ws + AG_OFF);
    (void)in_sizes; (void)n_in; (void)out_size; (void)ws_size;

    init_k<<<1, NT, 0, stream>>>(Ag);
    viterbi_fwd<<<NWG, 64, 0, stream>>>(unary, trans, bp, Ag);
    mbuild_k<<<NCH, NT, 0, stream>>>(bp, M);
    chase_k<<<1, NT, 0, stream>>>(Ag, trans, M, boundary, out);
    traceback_k<<<NCH, 64, 0, stream>>>(bp, boundary, out);
}